// Round 3
// baseline (46.538 us; speedup 1.0000x reference)
//
#include <hip/hip_runtime.h>
#include <math.h>

// Problem constants (match reference)
constexpr int   B_    = 2048;
constexpr int   L_    = 8192;
constexpr int   G_    = 256;
constexpr float BETA_ = 0.01f;
constexpr float BIG_  = 1024.0f;   // y-flag encoding (validated absmax 0.0 in prior rounds)

constexpr int   HALF  = L_ / 2;                 // 4096 labels per half-row
constexpr int   PMAX  = HALF + G_ * 3;          // padded rank space per half = 4864 floats

// log(sigmoid(-x)) = -softplus(x) = -(max(x,0) + log(1 + exp(-|x|)))
__device__ __forceinline__ float log_sigmoid_neg(float x) {
    return -(fmaxf(x, 0.0f) + __logf(1.0f + __expf(-fabsf(x))));
}

// ---------------------------------------------------------------------------
// Prep: counting sort into PADDED rank space, one block per HALF-row slab.
// offs[h][g+1]-offs[h][g] = ceil(n/4)*4 so main kernel can ds_read_b128.
// ---------------------------------------------------------------------------
extern "C" __global__ __launch_bounds__(1024)
void build_rank_kernel(const int* __restrict__ group_ids,
                       int* __restrict__ g_offs,            // [2][257]
                       unsigned short* __restrict__ g_rank) // [8192]
{
    __shared__ int s_cnt[G_];
    __shared__ int s_scan[G_];
    __shared__ int s_cur[G_];

    const int t = threadIdx.x;          // 0..1023
    const int h = blockIdx.x;           // 0..1

    if (t < G_) s_cnt[t] = 0;

    const int4 ids = ((const int4*)group_ids)[h * 1024 + t];   // 4 labels/thread
    __syncthreads();

    atomicAdd(&s_cnt[ids.x], 1);
    atomicAdd(&s_cnt[ids.y], 1);
    atomicAdd(&s_cnt[ids.z], 1);
    atomicAdd(&s_cnt[ids.w], 1);
    __syncthreads();

    if (t < G_) s_scan[t] = (s_cnt[t] + 3) & ~3;
    __syncthreads();
    for (int off = 1; off < G_; off <<= 1) {
        int v = 0;
        if (t < G_ && t >= off) v = s_scan[t - off];
        __syncthreads();
        if (t < G_) s_scan[t] += v;
        __syncthreads();
    }

    if (t < G_) {
        const int excl = s_scan[t] - ((s_cnt[t] + 3) & ~3);   // padded start
        s_cur[t] = excl;
        g_offs[h * 257 + t] = excl;
    }
    if (t == 0) g_offs[h * 257 + G_] = s_scan[G_ - 1];
    __syncthreads();

    const int l = h * HALF + t * 4;
    g_rank[l + 0] = (unsigned short)atomicAdd(&s_cur[ids.x], 1);
    g_rank[l + 1] = (unsigned short)atomicAdd(&s_cur[ids.y], 1);
    g_rank[l + 2] = (unsigned short)atomicAdd(&s_cur[ids.z], 1);
    g_rank[l + 3] = (unsigned short)atomicAdd(&s_cur[ids.w], 1);
}

// ---------------------------------------------------------------------------
// Main: 2048 blocks x 256 threads; block bid handles half h = bid&1 of rows
// {r0, r0+1024}, r0 = bid>>1.
//  - ranks + offsets hoisted to registers, reused for both rows
//  - whole half-row batch-prefetched into 32 VGPRs (8 loads in flight)
//  - row n+1's loads issued right after row n's scatter, kept in flight
//    across a RAW s_barrier (LDS-only lgkmcnt drain, no vmcnt(0) drain)
//  - padded LDS zero-init ONCE (pad slots never scattered to)
// ---------------------------------------------------------------------------
extern "C" __global__ __launch_bounds__(256, 8)
void meta_loss_kernel(const float* __restrict__ logits,
                      const int*   __restrict__ true_y,
                      const int*   __restrict__ g_offs,
                      const unsigned short* __restrict__ g_rank,
                      float*       __restrict__ partial)   // [B][G]
{
    __shared__ float s_row[PMAX];            // 19456 B

    const int t  = threadIdx.x;              // 0..255
    const int h  = blockIdx.x & 1;
    const int r0 = blockIdx.x >> 1;          // 0..1023

    // ---- block-invariant state in registers ----
    const ushort4* rk = (const ushort4*)(g_rank + h * HALF);
    ushort4 r[4];
    #pragma unroll
    for (int i = 0; i < 4; ++i) r[i] = rk[i * 256 + t];

    const int o0 = g_offs[h * 257 + t];
    const int o1 = g_offs[h * 257 + t + 1];

    // zero padded rank space once; pad slots stay 0 across both rows
    float4* s_row4 = (float4*)s_row;
    #pragma unroll
    for (int i = 0; i < 5; ++i) {
        const int j = i * 256 + t;
        if (j < PMAX / 4) s_row4[j] = make_float4(0.f, 0.f, 0.f, 0.f);
    }

    // ---- prefetch row 0 (8 independent 16B loads in flight) ----
    const float4* lg0 = (const float4*)(logits + (size_t)r0 * L_ + h * HALF);
    const int4*   ty0 = (const int4*)(true_y + (size_t)r0 * L_ + h * HALF);
    float4 X[4];
    int4   Y[4];
    #pragma unroll
    for (int i = 0; i < 4; ++i) { X[i] = lg0[i * 256 + t]; Y[i] = ty0[i * 256 + t]; }

    asm volatile("s_waitcnt lgkmcnt(0)" ::: "memory");
    __builtin_amdgcn_s_barrier();            // zero-init visible

    #pragma unroll
    for (int rr = 0; rr < 2; ++rr) {
        const int b = r0 + rr * 1024;

        // ---- scatter this row (compiler inserts vmcnt waits at first use) ----
        #pragma unroll
        for (int i = 0; i < 4; ++i) {
            s_row[r[i].x] = log_sigmoid_neg(X[i].x) + (Y[i].x ? BIG_ : 0.0f);
            s_row[r[i].y] = log_sigmoid_neg(X[i].y) + (Y[i].y ? BIG_ : 0.0f);
            s_row[r[i].z] = log_sigmoid_neg(X[i].z) + (Y[i].z ? BIG_ : 0.0f);
            s_row[r[i].w] = log_sigmoid_neg(X[i].w) + (Y[i].w ? BIG_ : 0.0f);
        }

        // ---- issue next row's loads; they stay in flight across the raw
        //      barrier + phase 2 (only lgkmcnt is drained, not vmcnt) ----
        if (rr == 0) {
            const int bn = r0 + 1024;
            const float4* lg = (const float4*)(logits + (size_t)bn * L_ + h * HALF);
            const int4*   ty = (const int4*)(true_y + (size_t)bn * L_ + h * HALF);
            #pragma unroll
            for (int i = 0; i < 4; ++i) { X[i] = lg[i * 256 + t]; Y[i] = ty[i * 256 + t]; }
        }

        asm volatile("s_waitcnt lgkmcnt(0)" ::: "memory");
        __builtin_amdgcn_s_barrier();        // scatter visible to all waves

        // ---- phase 2: contiguous per-group sum (all 256 threads) ----
        float4 a4 = make_float4(0.f, 0.f, 0.f, 0.f);
        for (int j = o0; j < o1; j += 4) {
            const float4 v = *(const float4*)&s_row[j];
            a4.x += v.x; a4.y += v.y; a4.z += v.z; a4.w += v.w;
        }
        const float enc = (a4.x + a4.y) + (a4.z + a4.w);
        if (o1 > o0)
            atomicAdd(&partial[b * G_ + t], enc);   // exactly 2 adders/address

        if (rr == 0) {
            // all phase-2 reads done (each wave consumed its data) before the
            // next row's scatter may overwrite slots
            asm volatile("s_waitcnt lgkmcnt(0)" ::: "memory");
            __builtin_amdgcn_s_barrier();
        }
    }
}

// ---------------------------------------------------------------------------
// Finalize: decode BIG encoding, BCE terms, global reduce. 2 MB read, tiny.
// ---------------------------------------------------------------------------
extern "C" __global__ __launch_bounds__(1024)
void finalize_kernel(const float* __restrict__ partial,
                     float* __restrict__ out)
{
    __shared__ float s_part[16];

    const int t   = threadIdx.x;
    const int idx = blockIdx.x * 1024 + t;    // 512 blocks x 1024 = 524288

    const float enc = partial[idx];
    const int   k   = __float2int_rn(enc * (1.0f / BIG_));   // # true labels
    const float gl  = enc - BIG_ * (float)k;                 // sum log(1-sig)

    float term;
    if (k != 0) {
        term = fmaxf(gl, -100.0f);                    // meta_y = 1: log(p)
    } else {
        // empty/all-false group: gl==0 -> log1p(-1) = -inf -> clamp to -100
        term = fmaxf(log1pf(-__expf(gl)), -100.0f);   // meta_y = 0
    }

    #pragma unroll
    for (int off = 32; off > 0; off >>= 1)
        term += __shfl_down(term, off, 64);
    if ((t & 63) == 0) s_part[t >> 6] = term;
    __syncthreads();

    if (t == 0) {
        float s = 0.0f;
        #pragma unroll
        for (int w = 0; w < 16; ++w) s += s_part[w];
        atomicAdd(out, s * (-BETA_ / ((float)B_ * (float)G_)));
    }
}

extern "C" void kernel_launch(void* const* d_in, const int* in_sizes, int n_in,
                              void* d_out, int out_size, void* d_ws, size_t ws_size,
                              hipStream_t stream) {
    const float* logits    = (const float*)d_in[0];
    const int*   true_y    = (const int*)d_in[1];
    const int*   group_ids = (const int*)d_in[2];
    float*       out       = (float*)d_out;

    // workspace: [0,2MB) partial f32; [2MB,+16KB) rank u16; then offs
    float*          partial = (float*)d_ws;
    unsigned short* g_rank  = (unsigned short*)((char*)d_ws + (size_t)B_ * G_ * 4);
    int*            g_offs  = (int*)((char*)d_ws + (size_t)B_ * G_ * 4 + L_ * 2);

    hipMemsetAsync(partial, 0, (size_t)B_ * G_ * 4, stream);
    hipMemsetAsync(out, 0, sizeof(float), stream);

    build_rank_kernel<<<2, 1024, 0, stream>>>(group_ids, g_offs, g_rank);
    meta_loss_kernel<<<2 * B_ / 2, 256, 0, stream>>>(logits, true_y, g_offs, g_rank, partial);
    finalize_kernel<<<(B_ * G_) / 1024, 1024, 0, stream>>>(partial, out);
}